// Round 1
// baseline (253.336 us; speedup 1.0000x reference)
//
#include <hip/hip_runtime.h>
#include <hip/hip_cooperative_groups.h>
#include <stdint.h>

namespace cg = cooperative_groups;

// DBSCAN-on-voxel-grid, exact port of the JAX reference for batch_size==1.
// Grid 512x512, eps=1.5 => 8-connected adjacency, min_samples=5 (voxels,
// incl. self), clusters with <20 voxels dropped.
// R7 = R6 fused into ONE cooperative kernel (6 phases + grid syncs).
// Rationale: total state is ~167 KB (L2-resident, FETCH_SIZE=14.5KB);
// the 7-dispatch pipeline was launch/serialization-bound, not BW/ALU-bound.

#define GRIDW 512
#define WPR 16        // bitmap words per row
#define NWORDS 8192   // 512*512/32
#define NCELLS 262144
#define NONE 0xFFFFFFFFu

// ---- ws layout (uint32 units) ----
#define OFF_OCC    0       // 8192: occupancy bitmap
#define OFF_CNT    8192    // 8192: per-root voxel counts
#define OFF_ROOTBM 16384   // 256
#define OFF_KEEPBM 16640   // 256
#define OFF_CM     16896   // 8192: core mask per word
#define OFF_LAB    25088   // 8192: union-find / final labels (by rank)
#define OFF_PRE    33280   // 8192: exclusive voxel-rank prefix per word
#define OFF_RPRE   41472   // 256: exclusive root-rank prefix per rootbm word

// per-position horizontal (west+self+east) 2-bit counts for a row of 32 cells
__device__ __forceinline__ void hsum(uint32_t l, uint32_t c, uint32_t r,
                                     uint32_t& h0, uint32_t& h1) {
  uint32_t Wb = (c << 1) | (l >> 31);
  uint32_t Eb = (c >> 1) | (r << 31);
  h0 = Wb ^ c ^ Eb;
  h1 = (Wb & c) | (Eb & (Wb ^ c));
}

// per-position (sum of three 2-bit row counts) >= 5 (bit-sliced adders)
__device__ __forceinline__ uint32_t ge5(uint32_t a0, uint32_t a1, uint32_t b0,
                                        uint32_t b1, uint32_t c0, uint32_t c1) {
  uint32_t u0 = a0 ^ b0, cy = a0 & b0;
  uint32_t t = a1 ^ b1;
  uint32_t u1 = t ^ cy;
  uint32_t u2 = (a1 & b1) | (cy & t);
  uint32_t v0 = u0 ^ c0, k0 = u0 & c0;
  uint32_t t2 = u1 ^ c1;
  uint32_t v1 = t2 ^ k0;
  uint32_t k1 = (u1 & c1) | (k0 & t2);
  uint32_t v2 = u2 ^ k1;
  uint32_t v3 = u2 & k1;
  return v3 | (v2 & (v1 | v0));  // count in {5..9}
}

__device__ __forceinline__ uint32_t aread(uint32_t* p) {
  return __hip_atomic_load(p, __ATOMIC_RELAXED, __HIP_MEMORY_SCOPE_AGENT);
}

// find root with guarded path compression: links are only ever LOWERED
// (write r into L[x] only while r < current link), preserving the
// monotone-decreasing invariant => no cycles, guaranteed termination.
__device__ __forceinline__ uint32_t findc(uint32_t* L, uint32_t x) {
  uint32_t r = x, p = aread(&L[r]);
  while (p != r) { r = p; p = aread(&L[r]); }
  while (x > r) {
    uint32_t nx = aread(&L[x]);
    if (nx <= r) break;          // someone already lowered it at least as far
    atomicCAS(&L[x], nx, r);     // best effort, only writes a smaller value
    x = nx;
  }
  return r;
}

// link larger root under smaller => final root == min core rank of component
__device__ __forceinline__ void unite(uint32_t* L, uint32_t a, uint32_t b) {
  for (;;) {
    a = findc(L, a);
    b = findc(L, b);
    if (a == b) return;
    uint32_t lo = min(a, b), hi = max(a, b);
    if (atomicCAS(&L[hi], hi, lo) == hi) return;  // hi still root => linked
    a = lo; b = hi;
  }
}

__global__ __launch_bounds__(256) void k_all(const float* __restrict__ pts,
                                             uint32_t* __restrict__ ws,
                                             float* __restrict__ out,
                                             int npts) {
  cg::grid_group grid = cg::this_grid();
  const int tid = threadIdx.x;
  const int gtid = blockIdx.x * 256 + tid;
  const int T = gridDim.x * 256;
  __shared__ uint32_t wsum[4];
  __shared__ int smax;

  // ---- P0: zero occ/cnt, init union-find labels, zero root/keep bitmaps ----
  for (int i = gtid; i < NWORDS; i += T) {
    ws[OFF_OCC + i] = 0u;
    ws[OFF_CNT + i] = 0u;
    ws[OFF_LAB + i] = (uint32_t)i;
  }
  if (gtid < 256) { ws[OFF_ROOTBM + gtid] = 0u; ws[OFF_KEEPBM + gtid] = 0u; }
  grid.sync();

  // ---- P1: voxelize points -> occupancy bits (identical f32 ops to jnp) ----
  for (int i = gtid; i < npts; i += T) {
    float x = pts[i * 5 + 1];
    float y = pts[i * 5 + 2];
    int cx = (int)floorf((x - (-51.2f)) / 0.2f);
    int cy = (int)floorf((y - (-51.2f)) / 0.2f);
    cx = min(max(cx, 0), GRIDW - 1);
    cy = min(max(cy, 0), GRIDW - 1);
    int cell = cy * GRIDW + cx;
    atomicOr(&ws[OFF_OCC + (cell >> 5)], 1u << (cell & 31));
  }
  grid.sync();

  // ---- P2: block 0 = voxel-rank prefix; other blocks = core masks ----
  const uint32_t* occ = ws + OFF_OCC;
  if (blockIdx.x == 0) {
    int base = tid * 32;
    uint32_t s = 0;
    for (int j = 0; j < 32; j++) s += __popc(occ[base + j]);
    int lane = tid & 63, wv = tid >> 6;
    uint32_t inc = s;
    for (int d = 1; d < 64; d <<= 1) { uint32_t t = __shfl_up(inc, d); if (lane >= d) inc += t; }
    if (lane == 63) wsum[wv] = inc;
    __syncthreads();
    uint32_t woff = 0;
    for (int k = 0; k < wv; k++) woff += wsum[k];
    uint32_t excl = woff + inc - s;
    uint32_t* pre = ws + OFF_PRE;
    for (int j = 0; j < 32; j++) { pre[base + j] = excl; excl += __popc(occ[base + j]); }
  } else {
    int wi = gtid - 256;
    if (wi < NWORDS) {
      uint32_t cB = occ[wi];
      int y = wi >> 4, wx = wi & 15;
      uint32_t lB = wx ? occ[wi - 1] : 0u;
      uint32_t rB = (wx < 15) ? occ[wi + 1] : 0u;
      uint32_t cA = 0, lA = 0, rA = 0, cC = 0, lC = 0, rC = 0;
      if (y > 0) { int wa = wi - WPR; cA = occ[wa]; lA = wx ? occ[wa - 1] : 0u; rA = (wx < 15) ? occ[wa + 1] : 0u; }
      if (y < GRIDW - 1) { int wc = wi + WPR; cC = occ[wc]; lC = wx ? occ[wc - 1] : 0u; rC = (wx < 15) ? occ[wc + 1] : 0u; }
      uint32_t a0, a1, b0, b1, c0, c1;
      hsum(lA, cA, rA, a0, a1); hsum(lB, cB, rB, b0, b1); hsum(lC, cC, rC, c0, c1);
      ws[OFF_CM + wi] = ge5(a0, a1, b0, b1, c0, c1) & cB;
    }
  }
  grid.sync();

  // ---- P3: per-cell union of core-core edges (E, S, SE, SW forward) ----
  const uint32_t* cm = ws + OFF_CM;
  const uint32_t* pre = ws + OFF_PRE;
  uint32_t* lab = ws + OFF_LAB;
  for (int cell = gtid; cell < NCELLS; cell += T) {
    int wi = cell >> 5, b = cell & 31, wx = wi & 15;
    uint32_t cw = cm[wi];
    if (!((cw >> b) & 1)) continue;
    int y = cell >> 9;
    uint32_t cB = occ[wi];
    int r = pre[wi] + __popc(cB & ((1u << b) - 1u));
    bool eC = (b < 31) ? ((cw >> (b + 1)) & 1) : ((wx < 15) ? (cm[wi + 1] & 1) : false);
    if (eC) unite(lab, r, (b < 31) ? r + 1 : pre[wi + 1]);
    if (y < GRIDW - 1) {
      uint32_t cmS = cm[wi + WPR];
      uint32_t occS = occ[wi + WPR];
      int rS = pre[wi + WPR];
      if ((cmS >> b) & 1) unite(lab, r, rS + __popc(occS & ((1u << b) - 1u)));
      bool seC = (b < 31) ? ((cmS >> (b + 1)) & 1) : ((wx < 15) ? (cm[wi + WPR + 1] & 1) : false);
      if (seC) unite(lab, r, (b < 31) ? rS + __popc(occS & ((2u << b) - 1u)) : pre[wi + WPR + 1]);
      bool swC = (b > 0) ? ((cmS >> (b - 1)) & 1) : ((wx > 0) ? (cm[wi + WPR - 1] >> 31) : false);
      if (swC) unite(lab, r, (b > 0) ? rS + __popc(occS & ((1u << (b - 1)) - 1u)) : rS - 1);
    }
  }
  grid.sync();

  // ---- P4: per-cell compress (core) + border attach (non-core) + counts ----
  uint32_t* cnt = ws + OFF_CNT;
  for (int cell = gtid; cell < NCELLS; cell += T) {
    int wi = cell >> 5, b = cell & 31, wx = wi & 15;
    uint32_t cB = occ[wi];
    if (!((cB >> b) & 1)) continue;
    int y = cell >> 9;
    uint32_t cw = cm[wi];
    int r = pre[wi] + __popc(cB & ((1u << b) - 1u));
    if ((cw >> b) & 1) {
      uint32_t root = findc(lab, r);
      lab[r] = root;
      if (root == (uint32_t)r) atomicOr(&ws[OFF_ROOTBM + (r >> 5)], 1u << (r & 31));
      atomicAdd(&cnt[root], 1u);
    } else {
      uint32_t m = NONE;
      bool wC = (b > 0) ? ((cw >> (b - 1)) & 1) : ((wx > 0) ? (cm[wi - 1] >> 31) : false);
      if (wC) m = min(m, findc(lab, (b > 0) ? r - 1 : (int)pre[wi] - 1));
      bool eC = (b < 31) ? ((cw >> (b + 1)) & 1) : ((wx < 15) ? (cm[wi + 1] & 1) : false);
      if (eC) m = min(m, findc(lab, (b < 31) ? r + 1 : pre[wi + 1]));
      if (y > 0) {
        uint32_t cmN = cm[wi - WPR], occN = occ[wi - WPR];
        int rN = pre[wi - WPR];
        if ((cmN >> b) & 1) m = min(m, findc(lab, rN + __popc(occN & ((1u << b) - 1u))));
        bool neC = (b < 31) ? ((cmN >> (b + 1)) & 1) : ((wx < 15) ? (cm[wi - WPR + 1] & 1) : false);
        if (neC) m = min(m, findc(lab, (b < 31) ? rN + __popc(occN & ((2u << b) - 1u)) : pre[wi - WPR + 1]));
        bool nwC = (b > 0) ? ((cmN >> (b - 1)) & 1) : ((wx > 0) ? (cm[wi - WPR - 1] >> 31) : false);
        if (nwC) m = min(m, findc(lab, (b > 0) ? rN + __popc(occN & ((1u << (b - 1)) - 1u)) : rN - 1));
      }
      if (y < GRIDW - 1) {
        uint32_t cmS = cm[wi + WPR], occS = occ[wi + WPR];
        int rS = pre[wi + WPR];
        if ((cmS >> b) & 1) m = min(m, findc(lab, rS + __popc(occS & ((1u << b) - 1u))));
        bool seC = (b < 31) ? ((cmS >> (b + 1)) & 1) : ((wx < 15) ? (cm[wi + WPR + 1] & 1) : false);
        if (seC) m = min(m, findc(lab, (b < 31) ? rS + __popc(occS & ((2u << b) - 1u)) : pre[wi + WPR + 1]));
        bool swC = (b > 0) ? ((cmS >> (b - 1)) & 1) : ((wx > 0) ? (cm[wi + WPR - 1] >> 31) : false);
        if (swC) m = min(m, findc(lab, (b > 0) ? rS + __popc(occS & ((1u << (b - 1)) - 1u)) : rS - 1));
      }
      lab[r] = m;  // NONE => noise; non-core ranks are never union-find parents
      if (m != NONE) atomicAdd(&cnt[m], 1u);
    }
  }
  grid.sync();

  // ---- P5 (block 0): dense root numbering, keep filter, max id -> out[npts]
  if (blockIdx.x == 0) {
    if (tid == 0) smax = -1;
    __syncthreads();
    uint32_t rb = ws[OFF_ROOTBM + tid];
    uint32_t v = __popc(rb);
    int lane = tid & 63, wv = tid >> 6;
    uint32_t inc = v;
    for (int d = 1; d < 64; d <<= 1) { uint32_t t = __shfl_up(inc, d); if (lane >= d) inc += t; }
    if (lane == 63) wsum[wv] = inc;
    __syncthreads();
    uint32_t woff = 0;
    for (int k = 0; k < wv; k++) woff += wsum[k];
    uint32_t excl = woff + inc - v;
    ws[OFF_RPRE + tid] = excl;
    uint32_t keep = 0;
    int mx = -1, d = (int)excl;
    while (rb) {
      int b = __ffs(rb) - 1; rb &= rb - 1;
      int rr = tid * 32 + b;
      if (ws[OFF_CNT + rr] >= 20u) { keep |= 1u << b; mx = d; }
      d++;
    }
    ws[OFF_KEEPBM + tid] = keep;
    if (mx >= 0) atomicMax(&smax, mx);
    __syncthreads();
    if (tid == 0) out[npts] = (float)(smax + 1);
  }
  grid.sync();

  // ---- P6: scatter dense labels back to points ----
  for (int i = gtid; i < npts; i += T) {
    float x = pts[i * 5 + 1];
    float y = pts[i * 5 + 2];
    int cx = (int)floorf((x - (-51.2f)) / 0.2f);  // identical math to P1
    int cy = (int)floorf((y - (-51.2f)) / 0.2f);
    cx = min(max(cx, 0), GRIDW - 1);
    cy = min(max(cy, 0), GRIDW - 1);
    int cell = cy * GRIDW + cx;
    int wi = cell >> 5;
    int r = ws[OFF_PRE + wi] + __popc(ws[OFF_OCC + wi] & ((1u << (cell & 31)) - 1u));
    uint32_t l = ws[OFF_LAB + r];
    float o = -1.0f;
    if (l != NONE && ((ws[OFF_KEEPBM + (l >> 5)] >> (l & 31)) & 1)) {
      int dnum = ws[OFF_RPRE + (l >> 5)] +
                 __popc(ws[OFF_ROOTBM + (l >> 5)] & ((1u << (l & 31)) - 1u));
      o = (float)dnum;
    }
    out[i] = o;
  }
}

extern "C" void kernel_launch(void* const* d_in, const int* in_sizes, int n_in,
                              void* d_out, int out_size, void* d_ws, size_t ws_size,
                              hipStream_t stream) {
  const float* pts = (const float*)d_in[0];
  int npts = in_sizes[0] / 5;  // points are (N,5) float32
  uint32_t* ws = (uint32_t*)d_ws;
  float* out = (float*)d_out;
  void* args[] = {(void*)&pts, (void*)&ws, (void*)&out, (void*)&npts};
  hipLaunchCooperativeKernel(reinterpret_cast<void*>(k_all), dim3(256),
                             dim3(256), args, 0, stream);
}

// Round 2
// 166.900 us; speedup vs baseline: 1.5179x; 1.5179x over previous
//
#include <hip/hip_runtime.h>
#include <stdint.h>

// DBSCAN-on-voxel-grid, exact port of the JAX reference for batch_size==1.
// Grid 512x512, eps=1.5 => 8-connected adjacency, min_samples=5 (voxels,
// incl. self), clusters with <20 voxels dropped.
// R8 = R7's single-kernel fusion, but:
//  - regular (graph-capturable) launch of 64 blocks; co-residency is
//    guaranteed by construction (64 blocks, 256 CUs, 1+ block/CU resources)
//  - hand-rolled arrival barriers (release-RMW + acquire-spin, agent scope)
//    instead of cg::grid().sync() (~25us each in R7)
//  - barrier counters + occ zeroed by one 33KB hipMemsetAsync, which also
//    removes the P0->P1 barrier (5 barriers total).

#define GRIDW 512
#define WPR 16        // bitmap words per row
#define NWORDS 8192   // 512*512/32
#define NCELLS 262144
#define NONE 0xFFFFFFFFu
#define NB 64         // blocks; must stay <= CU count for co-residency

// ---- ws layout (uint32 units) ----
#define OFF_OCC    0       // 8192: occupancy bitmap        (memset)
#define OFF_BAR    8192    // 128: barrier counters, 16-word spaced (memset)
#define OFF_CNT    8320    // 8192: per-root voxel counts   (zeroed in-kernel)
#define OFF_ROOTBM 16512   // 256                            (zeroed in-kernel)
#define OFF_KEEPBM 16768   // 256                            (zeroed in-kernel)
#define OFF_CM     17024   // 8192: core mask per word
#define OFF_LAB    25216   // 8192: union-find / final labels (by rank)
#define OFF_PRE    33408   // 8192: exclusive voxel-rank prefix per word
#define OFF_RPRE   41600   // 256: exclusive root-rank prefix per rootbm word
#define MEMSET_BYTES ((8192 + 128) * 4)

// device-wide arrival barrier: each block's tid0 does a RELEASE add (writes
// back its dirty L2 to the coherence point), then ACQUIRE-spins until all
// NB blocks arrived (invalidating stale cache so post-barrier reads are
// coherent). Counters are per-phase (fresh zeroed slot), no sense reversal.
__device__ __forceinline__ void gsync(uint32_t* ws, int idx) {
  __syncthreads();
  if (threadIdx.x == 0) {
    uint32_t* c = ws + OFF_BAR + idx * 16;
    __hip_atomic_fetch_add(c, 1u, __ATOMIC_RELEASE, __HIP_MEMORY_SCOPE_AGENT);
    while (__hip_atomic_load(c, __ATOMIC_ACQUIRE, __HIP_MEMORY_SCOPE_AGENT) <
           (uint32_t)NB) {
      __builtin_amdgcn_s_sleep(1);
    }
  }
  __syncthreads();
}

// per-position horizontal (west+self+east) 2-bit counts for a row of 32 cells
__device__ __forceinline__ void hsum(uint32_t l, uint32_t c, uint32_t r,
                                     uint32_t& h0, uint32_t& h1) {
  uint32_t Wb = (c << 1) | (l >> 31);
  uint32_t Eb = (c >> 1) | (r << 31);
  h0 = Wb ^ c ^ Eb;
  h1 = (Wb & c) | (Eb & (Wb ^ c));
}

// per-position (sum of three 2-bit row counts) >= 5 (bit-sliced adders)
__device__ __forceinline__ uint32_t ge5(uint32_t a0, uint32_t a1, uint32_t b0,
                                        uint32_t b1, uint32_t c0, uint32_t c1) {
  uint32_t u0 = a0 ^ b0, cy = a0 & b0;
  uint32_t t = a1 ^ b1;
  uint32_t u1 = t ^ cy;
  uint32_t u2 = (a1 & b1) | (cy & t);
  uint32_t v0 = u0 ^ c0, k0 = u0 & c0;
  uint32_t t2 = u1 ^ c1;
  uint32_t v1 = t2 ^ k0;
  uint32_t k1 = (u1 & c1) | (k0 & t2);
  uint32_t v2 = u2 ^ k1;
  uint32_t v3 = u2 & k1;
  return v3 | (v2 & (v1 | v0));  // count in {5..9}
}

__device__ __forceinline__ uint32_t aread(uint32_t* p) {
  return __hip_atomic_load(p, __ATOMIC_RELAXED, __HIP_MEMORY_SCOPE_AGENT);
}

// find root with guarded path compression: links are only ever LOWERED
// (write r into L[x] only while r < current link), preserving the
// monotone-decreasing invariant => no cycles, guaranteed termination.
__device__ __forceinline__ uint32_t findc(uint32_t* L, uint32_t x) {
  uint32_t r = x, p = aread(&L[r]);
  while (p != r) { r = p; p = aread(&L[r]); }
  while (x > r) {
    uint32_t nx = aread(&L[x]);
    if (nx <= r) break;          // someone already lowered it at least as far
    atomicCAS(&L[x], nx, r);     // best effort, only writes a smaller value
    x = nx;
  }
  return r;
}

// link larger root under smaller => final root == min core rank of component
__device__ __forceinline__ void unite(uint32_t* L, uint32_t a, uint32_t b) {
  for (;;) {
    a = findc(L, a);
    b = findc(L, b);
    if (a == b) return;
    uint32_t lo = min(a, b), hi = max(a, b);
    if (atomicCAS(&L[hi], hi, lo) == hi) return;  // hi still root => linked
    a = lo; b = hi;
  }
}

__global__ __launch_bounds__(256, 1) void k_all(const float* __restrict__ pts,
                                                uint32_t* __restrict__ ws,
                                                float* __restrict__ out,
                                                int npts) {
  const int tid = threadIdx.x;
  const int gtid = blockIdx.x * 256 + tid;
  const int T = NB * 256;
  __shared__ uint32_t wsum[4];
  __shared__ int smax;

  // ---- PA: zero cnt, init union-find labels, zero root/keep bitmaps,
  //          voxelize points -> occupancy bits (occ pre-zeroed by memset;
  //          no barrier needed between the zeroing and the atomicOr since
  //          they touch disjoint arrays) ----
  for (int i = gtid; i < NWORDS; i += T) {
    ws[OFF_CNT + i] = 0u;
    ws[OFF_LAB + i] = (uint32_t)i;
  }
  if (gtid < 256) { ws[OFF_ROOTBM + gtid] = 0u; ws[OFF_KEEPBM + gtid] = 0u; }
  for (int i = gtid; i < npts; i += T) {
    float x = pts[i * 5 + 1];
    float y = pts[i * 5 + 2];
    int cx = (int)floorf((x - (-51.2f)) / 0.2f);
    int cy = (int)floorf((y - (-51.2f)) / 0.2f);
    cx = min(max(cx, 0), GRIDW - 1);
    cy = min(max(cy, 0), GRIDW - 1);
    int cell = cy * GRIDW + cx;
    atomicOr(&ws[OFF_OCC + (cell >> 5)], 1u << (cell & 31));
  }
  gsync(ws, 0);

  // ---- PB: block 0 = voxel-rank prefix; other blocks = core masks ----
  const uint32_t* occ = ws + OFF_OCC;
  if (blockIdx.x == 0) {
    int base = tid * 32;
    uint32_t s = 0;
    for (int j = 0; j < 32; j++) s += __popc(occ[base + j]);
    int lane = tid & 63, wv = tid >> 6;
    uint32_t inc = s;
    for (int d = 1; d < 64; d <<= 1) { uint32_t t = __shfl_up(inc, d); if (lane >= d) inc += t; }
    if (lane == 63) wsum[wv] = inc;
    __syncthreads();
    uint32_t woff = 0;
    for (int k = 0; k < wv; k++) woff += wsum[k];
    uint32_t excl = woff + inc - s;
    uint32_t* pre = ws + OFF_PRE;
    for (int j = 0; j < 32; j++) { pre[base + j] = excl; excl += __popc(occ[base + j]); }
  } else {
    int wi = gtid - 256;
    if (wi < NWORDS) {
      uint32_t cB = occ[wi];
      int y = wi >> 4, wx = wi & 15;
      uint32_t lB = wx ? occ[wi - 1] : 0u;
      uint32_t rB = (wx < 15) ? occ[wi + 1] : 0u;
      uint32_t cA = 0, lA = 0, rA = 0, cC = 0, lC = 0, rC = 0;
      if (y > 0) { int wa = wi - WPR; cA = occ[wa]; lA = wx ? occ[wa - 1] : 0u; rA = (wx < 15) ? occ[wa + 1] : 0u; }
      if (y < GRIDW - 1) { int wc = wi + WPR; cC = occ[wc]; lC = wx ? occ[wc - 1] : 0u; rC = (wx < 15) ? occ[wc + 1] : 0u; }
      uint32_t a0, a1, b0, b1, c0, c1;
      hsum(lA, cA, rA, a0, a1); hsum(lB, cB, rB, b0, b1); hsum(lC, cC, rC, c0, c1);
      ws[OFF_CM + wi] = ge5(a0, a1, b0, b1, c0, c1) & cB;
    }
  }
  gsync(ws, 1);

  // ---- PC: per-cell union of core-core edges (E, S, SE, SW forward) ----
  const uint32_t* cm = ws + OFF_CM;
  const uint32_t* pre = ws + OFF_PRE;
  uint32_t* lab = ws + OFF_LAB;
  for (int cell = gtid; cell < NCELLS; cell += T) {
    int wi = cell >> 5, b = cell & 31, wx = wi & 15;
    uint32_t cw = cm[wi];
    if (!((cw >> b) & 1)) continue;
    int y = cell >> 9;
    uint32_t cB = occ[wi];
    int r = pre[wi] + __popc(cB & ((1u << b) - 1u));
    bool eC = (b < 31) ? ((cw >> (b + 1)) & 1) : ((wx < 15) ? (cm[wi + 1] & 1) : false);
    if (eC) unite(lab, r, (b < 31) ? r + 1 : pre[wi + 1]);
    if (y < GRIDW - 1) {
      uint32_t cmS = cm[wi + WPR];
      uint32_t occS = occ[wi + WPR];
      int rS = pre[wi + WPR];
      if ((cmS >> b) & 1) unite(lab, r, rS + __popc(occS & ((1u << b) - 1u)));
      bool seC = (b < 31) ? ((cmS >> (b + 1)) & 1) : ((wx < 15) ? (cm[wi + WPR + 1] & 1) : false);
      if (seC) unite(lab, r, (b < 31) ? rS + __popc(occS & ((2u << b) - 1u)) : pre[wi + WPR + 1]);
      bool swC = (b > 0) ? ((cmS >> (b - 1)) & 1) : ((wx > 0) ? (cm[wi + WPR - 1] >> 31) : false);
      if (swC) unite(lab, r, (b > 0) ? rS + __popc(occS & ((1u << (b - 1)) - 1u)) : rS - 1);
    }
  }
  gsync(ws, 2);

  // ---- PD: per-cell compress (core) + border attach (non-core) + counts ----
  uint32_t* cnt = ws + OFF_CNT;
  for (int cell = gtid; cell < NCELLS; cell += T) {
    int wi = cell >> 5, b = cell & 31, wx = wi & 15;
    uint32_t cB = occ[wi];
    if (!((cB >> b) & 1)) continue;
    int y = cell >> 9;
    uint32_t cw = cm[wi];
    int r = pre[wi] + __popc(cB & ((1u << b) - 1u));
    if ((cw >> b) & 1) {
      uint32_t root = findc(lab, r);
      lab[r] = root;
      if (root == (uint32_t)r) atomicOr(&ws[OFF_ROOTBM + (r >> 5)], 1u << (r & 31));
      atomicAdd(&cnt[root], 1u);
    } else {
      uint32_t m = NONE;
      bool wC = (b > 0) ? ((cw >> (b - 1)) & 1) : ((wx > 0) ? (cm[wi - 1] >> 31) : false);
      if (wC) m = min(m, findc(lab, (b > 0) ? r - 1 : (int)pre[wi] - 1));
      bool eC = (b < 31) ? ((cw >> (b + 1)) & 1) : ((wx < 15) ? (cm[wi + 1] & 1) : false);
      if (eC) m = min(m, findc(lab, (b < 31) ? r + 1 : pre[wi + 1]));
      if (y > 0) {
        uint32_t cmN = cm[wi - WPR], occN = occ[wi - WPR];
        int rN = pre[wi - WPR];
        if ((cmN >> b) & 1) m = min(m, findc(lab, rN + __popc(occN & ((1u << b) - 1u))));
        bool neC = (b < 31) ? ((cmN >> (b + 1)) & 1) : ((wx < 15) ? (cm[wi - WPR + 1] & 1) : false);
        if (neC) m = min(m, findc(lab, (b < 31) ? rN + __popc(occN & ((2u << b) - 1u)) : pre[wi - WPR + 1]));
        bool nwC = (b > 0) ? ((cmN >> (b - 1)) & 1) : ((wx > 0) ? (cm[wi - WPR - 1] >> 31) : false);
        if (nwC) m = min(m, findc(lab, (b > 0) ? rN + __popc(occN & ((1u << (b - 1)) - 1u)) : rN - 1));
      }
      if (y < GRIDW - 1) {
        uint32_t cmS = cm[wi + WPR], occS = occ[wi + WPR];
        int rS = pre[wi + WPR];
        if ((cmS >> b) & 1) m = min(m, findc(lab, rS + __popc(occS & ((1u << b) - 1u))));
        bool seC = (b < 31) ? ((cmS >> (b + 1)) & 1) : ((wx < 15) ? (cm[wi + WPR + 1] & 1) : false);
        if (seC) m = min(m, findc(lab, (b < 31) ? rS + __popc(occS & ((2u << b) - 1u)) : pre[wi + WPR + 1]));
        bool swC = (b > 0) ? ((cmS >> (b - 1)) & 1) : ((wx > 0) ? (cm[wi + WPR - 1] >> 31) : false);
        if (swC) m = min(m, findc(lab, (b > 0) ? rS + __popc(occS & ((1u << (b - 1)) - 1u)) : rS - 1));
      }
      lab[r] = m;  // NONE => noise; non-core ranks are never union-find parents
      if (m != NONE) atomicAdd(&cnt[m], 1u);
    }
  }
  gsync(ws, 3);

  // ---- PE (block 0): dense root numbering, keep filter, max id -> out[npts]
  if (blockIdx.x == 0) {
    if (tid == 0) smax = -1;
    __syncthreads();
    uint32_t rb = ws[OFF_ROOTBM + tid];
    uint32_t v = __popc(rb);
    int lane = tid & 63, wv = tid >> 6;
    uint32_t inc = v;
    for (int d = 1; d < 64; d <<= 1) { uint32_t t = __shfl_up(inc, d); if (lane >= d) inc += t; }
    if (lane == 63) wsum[wv] = inc;
    __syncthreads();
    uint32_t woff = 0;
    for (int k = 0; k < wv; k++) woff += wsum[k];
    uint32_t excl = woff + inc - v;
    ws[OFF_RPRE + tid] = excl;
    uint32_t keep = 0;
    int mx = -1, d = (int)excl;
    while (rb) {
      int b = __ffs(rb) - 1; rb &= rb - 1;
      int rr = tid * 32 + b;
      if (ws[OFF_CNT + rr] >= 20u) { keep |= 1u << b; mx = d; }
      d++;
    }
    ws[OFF_KEEPBM + tid] = keep;
    if (mx >= 0) atomicMax(&smax, mx);
    __syncthreads();
    if (tid == 0) out[npts] = (float)(smax + 1);
  }
  gsync(ws, 4);

  // ---- PF: scatter dense labels back to points ----
  for (int i = gtid; i < npts; i += T) {
    float x = pts[i * 5 + 1];
    float y = pts[i * 5 + 2];
    int cx = (int)floorf((x - (-51.2f)) / 0.2f);  // identical math to PA
    int cy = (int)floorf((y - (-51.2f)) / 0.2f);
    cx = min(max(cx, 0), GRIDW - 1);
    cy = min(max(cy, 0), GRIDW - 1);
    int cell = cy * GRIDW + cx;
    int wi = cell >> 5;
    int r = ws[OFF_PRE + wi] + __popc(ws[OFF_OCC + wi] & ((1u << (cell & 31)) - 1u));
    uint32_t l = ws[OFF_LAB + r];
    float o = -1.0f;
    if (l != NONE && ((ws[OFF_KEEPBM + (l >> 5)] >> (l & 31)) & 1)) {
      int dnum = ws[OFF_RPRE + (l >> 5)] +
                 __popc(ws[OFF_ROOTBM + (l >> 5)] & ((1u << (l & 31)) - 1u));
      o = (float)dnum;
    }
    out[i] = o;
  }
}

extern "C" void kernel_launch(void* const* d_in, const int* in_sizes, int n_in,
                              void* d_out, int out_size, void* d_ws, size_t ws_size,
                              hipStream_t stream) {
  const float* pts = (const float*)d_in[0];
  int npts = in_sizes[0] / 5;  // points are (N,5) float32
  uint32_t* ws = (uint32_t*)d_ws;
  float* out = (float*)d_out;
  hipMemsetAsync(d_ws, 0, MEMSET_BYTES, stream);  // occ + barrier counters
  k_all<<<NB, 256, 0, stream>>>(pts, ws, out, npts);
}